// Round 1
// baseline (662.205 us; speedup 1.0000x reference)
//
#include <hip/hip_runtime.h>

// Problem constants (V, D, H, L, E) = (50000, 128, 128, 4, 160000)
#define V_NODES 50000
#define DIM     128
#define NEDGE   160000

typedef __bf16 bf16;
typedef __attribute__((ext_vector_type(8))) __bf16 bf16x8;
typedef __attribute__((ext_vector_type(4))) __bf16 bf16x4;
typedef __attribute__((ext_vector_type(4))) float  f32x4;

// ---------------- prep kernels: fp32 -> bf16 (weights transposed) ----------

__global__ __launch_bounds__(256) void prep_emb_k(const float* __restrict__ in,
                                                  bf16* __restrict__ out) {
  int i = blockIdx.x * 256 + threadIdx.x;           // one thread per 4 elems
  float4 v = ((const float4*)in)[i];
  bf16x4 o = {(bf16)v.x, (bf16)v.y, (bf16)v.z, (bf16)v.w};
  *(bf16x4*)(out + (size_t)i * 4) = o;
}

// W1: (4,2,256,128) -> W1T[g=l*2+ep][n(128)][k(256)] bf16
__global__ __launch_bounds__(256) void prep_w1_k(const float* __restrict__ in,
                                                 bf16* __restrict__ out) {
  int idx = blockIdx.x * 256 + threadIdx.x;         // 262144 total
  int n = idx & 127, k = (idx >> 7) & 255, g = idx >> 15;
  out[(((g << 7) + n) << 8) + k] = (bf16)in[idx];
}

// W2: (4,2,128,128) -> W2T[g][n(128)][k(128)] bf16
__global__ __launch_bounds__(256) void prep_w2_k(const float* __restrict__ in,
                                                 bf16* __restrict__ out) {
  int idx = blockIdx.x * 256 + threadIdx.x;         // 131072 total
  int n = idx & 127, k = (idx >> 7) & 127, g = idx >> 14;
  out[(((g << 7) + n) << 7) + k] = (bf16)in[idx];
}

__global__ __launch_bounds__(256) void relu_k(float* __restrict__ out) {
  int i = blockIdx.x * 256 + threadIdx.x;           // one thread per 4 elems
  float4 v = ((float4*)out)[i];
  v.x = fmaxf(v.x, 0.f); v.y = fmaxf(v.y, 0.f);
  v.z = fmaxf(v.z, 0.f); v.w = fmaxf(v.w, 0.f);
  ((float4*)out)[i] = v;
}

// ---------------- main edge kernel ----------------------------------------
// grid = 8 groups (l,ep) x 250 block-slices; each block: stage W1T/W2T in LDS,
// loop 10 tiles of 64 edges: gather raw -> GEMM1(relu) -> h -> GEMM2 -> scatter.
// Padded LDS rows: 256->264 (row shift 4 banks -> <=2-way conflicts, free),
// 128->136. Total LDS = 67584 + 34816 + 33792 + 17408 + 512 = 154112 B.

#define W1P 264   // padded K stride for 256-K rows
#define W2P 136   // padded K stride for 128-K rows

__global__ __launch_bounds__(256) void edge_k(
    const bf16* __restrict__ embB,
    const int* __restrict__ a0, const int* __restrict__ a1,
    const int* __restrict__ a2, const int* __restrict__ a3,
    const bf16* __restrict__ w1t, const bf16* __restrict__ w2t,
    float* __restrict__ out) {

  __shared__ __attribute__((aligned(16))) bf16 w1_lds[128 * W1P];
  __shared__ __attribute__((aligned(16))) bf16 w2_lds[128 * W2P];
  __shared__ __attribute__((aligned(16))) bf16 raw_lds[64 * W1P];
  __shared__ __attribute__((aligned(16))) bf16 h_lds[64 * W2P];
  __shared__ int2 adj_lds[64];

  const int tid = threadIdx.x;
  const int g  = blockIdx.x / 250;       // (l,ep) group 0..7
  const int bs = blockIdx.x % 250;       // tile slice
  const int l = g >> 1, ep = g & 1;
  const int* __restrict__ adj = (l == 0) ? a0 : (l == 1) ? a1 : (l == 2) ? a2 : a3;

  // ---- stage W1T (128 rows x 32 x 16B) and W2T (128 rows x 16 x 16B) ----
  {
    const uint4* w1g = (const uint4*)(w1t + (size_t)g * 128 * 256);
    #pragma unroll
    for (int i = 0; i < 16; ++i) {
      int c = i * 256 + tid;                 // 0..4095
      int n = c >> 5, kc = c & 31;
      *(uint4*)(&w1_lds[n * W1P + kc * 8]) = w1g[n * 32 + kc];
    }
    const uint4* w2g = (const uint4*)(w2t + (size_t)g * 128 * 128);
    #pragma unroll
    for (int i = 0; i < 8; ++i) {
      int c = i * 256 + tid;                 // 0..2047
      int n = c >> 4, kc = c & 15;
      *(uint4*)(&w2_lds[n * W2P + kc * 8]) = w2g[n * 16 + kc];
    }
  }

  const int w    = tid >> 6;               // wave 0..3
  const int lane = tid & 63;
  const int wr = w >> 1, wc = w & 1;       // 2x2 wave grid: 32 rows x 64 cols each
  const int l15 = lane & 15, q = lane >> 4;
  const uint4* embq = (const uint4*)embB;  // emb row = 16 x uint4

  for (int t = bs * 10; t < bs * 10 + 10; ++t) {
    __syncthreads();  // protect adj_lds/raw_lds from previous iter's readers

    if (tid < 64) adj_lds[tid] = ((const int2*)adj)[t * 64 + tid];

    // gather: 64 edges x 2 halves x 16 chunks(16B) = 2048 chunk jobs
    #pragma unroll
    for (int i = 0; i < 8; ++i) {
      int c = i * 256 + tid;
      int e = c >> 5, half = (c >> 4) & 1, ck = c & 15;
      int node = adj[(t * 64 + e) * 2 + half];
      uint4 v = embq[(size_t)node * 16 + ck];
      *(uint4*)(&raw_lds[e * W1P + half * 128 + ck * 8]) = v;
    }
    __syncthreads();  // staging+gather visible

    // ---- GEMM1: h[64x128] = relu(raw[64x256] @ W1[256x128]) ----
    f32x4 acc[2][4] = {};
    #pragma unroll
    for (int kb = 0; kb < 8; ++kb) {
      const int kk = kb * 32 + q * 8;
      bf16x8 a[2], b[4];
      #pragma unroll
      for (int mt = 0; mt < 2; ++mt)
        a[mt] = *(const bf16x8*)(&raw_lds[(32 * wr + 16 * mt + l15) * W1P + kk]);
      #pragma unroll
      for (int nt = 0; nt < 4; ++nt)
        b[nt] = *(const bf16x8*)(&w1_lds[(64 * wc + 16 * nt + l15) * W1P + kk]);
      #pragma unroll
      for (int mt = 0; mt < 2; ++mt)
        #pragma unroll
        for (int nt = 0; nt < 4; ++nt)
          acc[mt][nt] = __builtin_amdgcn_mfma_f32_16x16x32_bf16(a[mt], b[nt], acc[mt][nt], 0, 0, 0);
    }
    // relu + cvt + store h (C/D layout: row = q*4+r, col = lane&15)
    #pragma unroll
    for (int mt = 0; mt < 2; ++mt)
      #pragma unroll
      for (int nt = 0; nt < 4; ++nt)
        #pragma unroll
        for (int r = 0; r < 4; ++r) {
          float v = acc[mt][nt][r];
          v = v > 0.f ? v : 0.f;
          h_lds[(32 * wr + 16 * mt + q * 4 + r) * W2P + 64 * wc + 16 * nt + l15] = (bf16)v;
        }
    __syncthreads();  // h visible

    // ---- GEMM2: msg[64x128] = h[64x128] @ W2[128x128] ----
    f32x4 acc2[2][4] = {};
    #pragma unroll
    for (int kb = 0; kb < 4; ++kb) {
      const int kk = kb * 32 + q * 8;
      bf16x8 a[2], b[4];
      #pragma unroll
      for (int mt = 0; mt < 2; ++mt)
        a[mt] = *(const bf16x8*)(&h_lds[(32 * wr + 16 * mt + l15) * W2P + kk]);
      #pragma unroll
      for (int nt = 0; nt < 4; ++nt)
        b[nt] = *(const bf16x8*)(&w2_lds[(64 * wc + 16 * nt + l15) * W2P + kk]);
      #pragma unroll
      for (int mt = 0; mt < 2; ++mt)
        #pragma unroll
        for (int nt = 0; nt < 4; ++nt)
          acc2[mt][nt] = __builtin_amdgcn_mfma_f32_16x16x32_bf16(a[mt], b[nt], acc2[mt][nt], 0, 0, 0);
    }

    // ---- scatter: atomicAdd into out[target*128 + col] ----
    #pragma unroll
    for (int mt = 0; mt < 2; ++mt)
      #pragma unroll
      for (int r = 0; r < 4; ++r) {
        int row = 32 * wr + 16 * mt + q * 4 + r;
        int2 pr = adj_lds[row];
        int node = ep ? pr.y : pr.x;
        float* basep = out + (size_t)node * 128 + 64 * wc + l15;
        #pragma unroll
        for (int nt = 0; nt < 4; ++nt)
          unsafeAtomicAdd(basep + 16 * nt, acc2[mt][nt][r]);
      }
  }
}

// ---------------- host launch ----------------------------------------------

extern "C" void kernel_launch(void* const* d_in, const int* in_sizes, int n_in,
                              void* d_out, int out_size, void* d_ws, size_t ws_size,
                              hipStream_t stream) {
  const float* emb = (const float*)d_in[0];
  const int* a0 = (const int*)d_in[1];
  const int* a1 = (const int*)d_in[2];
  const int* a2 = (const int*)d_in[3];
  const int* a3 = (const int*)d_in[4];
  const float* W1 = (const float*)d_in[5];
  const float* W2 = (const float*)d_in[6];
  float* out = (float*)d_out;

  char* ws = (char*)d_ws;
  bf16* embB = (bf16*)ws;                      // 50000*128*2 = 12,800,000 B
  bf16* w1t  = (bf16*)(ws + 12800000);         // 262144*2    =    524,288 B
  bf16* w2t  = (bf16*)(ws + 13324288);         // 131072*2    =    262,144 B

  hipMemsetAsync(d_out, 0, (size_t)V_NODES * DIM * sizeof(float), stream);
  prep_emb_k<<<6250, 256, 0, stream>>>(emb, embB);   // 6.4M elems / 4 / 256
  prep_w1_k<<<1024, 256, 0, stream>>>(W1, w1t);
  prep_w2_k<<<512, 256, 0, stream>>>(W2, w2t);
  edge_k<<<2000, 256, 0, stream>>>(embB, a0, a1, a2, a3, w1t, w2t, out);
  relu_k<<<6250, 256, 0, stream>>>(out);
}

// Round 4
// 638.372 us; speedup vs baseline: 1.0373x; 1.0373x over previous
//
#include <hip/hip_runtime.h>

// (V, D, H, L, E) = (50000, 128, 128, 4, 160000)
#define V_NODES 50000
#define DIM     128
#define NEDGE   160000

typedef __bf16 bf16;
typedef __attribute__((ext_vector_type(8))) __bf16 bf16x8;
typedef __attribute__((ext_vector_type(4))) __bf16 bf16x4;
typedef __attribute__((ext_vector_type(4))) float  f32x4;

__device__ __forceinline__ int clampV(int n) {
  unsigned u = (unsigned)n;
  return (int)(u < (unsigned)V_NODES ? u : (unsigned)(V_NODES - 1));
}

// ---------------- prep kernels: fp32 -> bf16 (weights transposed) ----------

__global__ __launch_bounds__(256) void prep_emb_k(const float* __restrict__ in,
                                                  bf16* __restrict__ out) {
  int i = blockIdx.x * 256 + threadIdx.x;           // one thread per 4 elems
  float4 v = ((const float4*)in)[i];
  bf16x4 o = {(bf16)v.x, (bf16)v.y, (bf16)v.z, (bf16)v.w};
  *(bf16x4*)(out + (size_t)i * 4) = o;
}

// W1: (4,2,256,128) -> W1T[g=l*2+ep][n(128)][k(256)] bf16
__global__ __launch_bounds__(256) void prep_w1_k(const float* __restrict__ in,
                                                 bf16* __restrict__ out) {
  int idx = blockIdx.x * 256 + threadIdx.x;         // 262144 total
  int n = idx & 127, k = (idx >> 7) & 255, g = idx >> 15;
  out[(((g << 7) + n) << 8) + k] = (bf16)in[idx];
}

// W2: (4,2,128,128) -> W2T[g][n(128)][k(128)] bf16
__global__ __launch_bounds__(256) void prep_w2_k(const float* __restrict__ in,
                                                 bf16* __restrict__ out) {
  int idx = blockIdx.x * 256 + threadIdx.x;         // 131072 total
  int n = idx & 127, k = (idx >> 7) & 127, g = idx >> 14;
  out[(((g << 7) + n) << 7) + k] = (bf16)in[idx];
}

__global__ __launch_bounds__(256) void relu_k(float* __restrict__ out) {
  int i = blockIdx.x * 256 + threadIdx.x;           // one thread per 4 elems
  float4 v = ((float4*)out)[i];
  v.x = fmaxf(v.x, 0.f); v.y = fmaxf(v.y, 0.f);
  v.z = fmaxf(v.z, 0.f); v.w = fmaxf(v.w, 0.f);
  ((float4*)out)[i] = v;
}

// ---------------- main edge kernel ----------------------------------------
// LDS = W1 (64 KB, XOR-swizzled 16B chunks) + h (16 KB, swizzled) = 80 KB
// exactly -> 2 blocks/CU, 8 waves/CU. A1 fragments gathered direct from
// global emb (bf16, L2/L3-resident); W2 B-fragments streamed direct from
// global (L1-hot, 32 KB/group); adj read direct. 2 barriers per 64-edge tile.
// Swizzle: 16B chunk c of row n stored at chunk (c ^ (n & 7)); keeps
// ds_read_b128 fragments intact and spreads the 512B/256B row strides.
// FIX (R3): h-store column now includes the 64*wc wave-column offset —
// rounds 2/3 dropped it, causing inter-wave clobber + stale cols 64..127.

__global__ __launch_bounds__(256) void edge_k(
    const bf16* __restrict__ embB,
    const int* __restrict__ a0, const int* __restrict__ a1,
    const int* __restrict__ a2, const int* __restrict__ a3,
    const bf16* __restrict__ w1t, const bf16* __restrict__ w2t,
    float* __restrict__ out) {

  __shared__ __attribute__((aligned(16))) bf16 w1_lds[128 * 256]; // 65536 B
  __shared__ __attribute__((aligned(16))) bf16 h_lds[64 * 128];   // 16384 B

  const int tid = threadIdx.x;
  const int g  = blockIdx.x >> 6;        // (l,ep) group 0..7
  const int bs = blockIdx.x & 63;        // 64 blocks per group
  const int l = g >> 1, ep = g & 1;
  const int* __restrict__ adj = (l == 0) ? a0 : (l == 1) ? a1 : (l == 2) ? a2 : a3;

  // ---- stage W1T[g]: 128 n-rows x 32 chunks(16B), swizzled ----
  {
    const uint4* w1g = (const uint4*)(w1t + (size_t)g * 128 * 256);
    #pragma unroll
    for (int i = 0; i < 16; ++i) {
      int j = i * 256 + tid;                 // 0..4095 chunk jobs
      int n = j >> 5, c = j & 31;
      *(uint4*)(&w1_lds[n * 256 + ((c ^ (n & 7)) << 3)]) = w1g[j];
    }
  }
  __syncthreads();

  const int w    = tid >> 6;               // wave 0..3
  const int lane = tid & 63;
  const int wr = w >> 1, wc = w & 1;       // 2x2 wave grid: 32 rows x 64 cols
  const int l15 = lane & 15, q = lane >> 4;
  const bf16* __restrict__ w2g = w2t + (size_t)g * 128 * 128;

  for (int t = bs; t < 2500; t += 64) {
    const int ebase = t * 64;

    // adj pairs for this lane's A-fragment rows (mt=0,1)
    int2 pr0 = ((const int2*)adj)[ebase + 32 * wr + l15];
    int2 pr1 = ((const int2*)adj)[ebase + 32 * wr + 16 + l15];
    pr0.x = clampV(pr0.x); pr0.y = clampV(pr0.y);
    pr1.x = clampV(pr1.x); pr1.y = clampV(pr1.y);

    // ---- GEMM1: h[64x128] = relu(raw[64x256] @ W1[256x128]) ----
    // A direct from global: k<128 -> emb[src], k>=128 -> emb[dst]
    f32x4 acc[2][4] = {};
    #pragma unroll
    for (int kb = 0; kb < 8; ++kb) {
      const int k = kb * 32 + q * 8;
      const int klo = k & 127;
      const int n0 = (kb < 4) ? pr0.x : pr0.y;
      const int n1 = (kb < 4) ? pr1.x : pr1.y;
      bf16x8 a[2], b[4];
      a[0] = *(const bf16x8*)(embB + (size_t)n0 * 128 + klo);
      a[1] = *(const bf16x8*)(embB + (size_t)n1 * 128 + klo);
      const int csw = ((kb << 2) + q);     // chunk index k/8
      #pragma unroll
      for (int nt = 0; nt < 4; ++nt) {
        int n = 64 * wc + 16 * nt + l15;
        b[nt] = *(const bf16x8*)(&w1_lds[n * 256 + ((csw ^ (l15 & 7)) << 3)]);
      }
      #pragma unroll
      for (int mt = 0; mt < 2; ++mt)
        #pragma unroll
        for (int nt = 0; nt < 4; ++nt)
          acc[mt][nt] = __builtin_amdgcn_mfma_f32_16x16x32_bf16(a[mt], b[nt], acc[mt][nt], 0, 0, 0);
    }

    __syncthreads();  // previous tile's GEMM2 done reading h_lds

    // relu + cvt + store h (C/D layout: row = q*4+r, col = 64*wc+16*nt+l15)
    #pragma unroll
    for (int mt = 0; mt < 2; ++mt)
      #pragma unroll
      for (int nt = 0; nt < 4; ++nt)
        #pragma unroll
        for (int r = 0; r < 4; ++r) {
          float v = acc[mt][nt][r];
          v = v > 0.f ? v : 0.f;
          int row = 32 * wr + 16 * mt + 4 * q + r;
          int col = 64 * wc + 16 * nt + l15;   // FIX: include 64*wc
          int c = col >> 3;
          h_lds[row * 128 + (((c ^ (row & 7)) << 3) | (col & 7))] = (bf16)v;
        }
    __syncthreads();  // h visible

    // ---- GEMM2: msg[64x128] = h[64x128] @ W2[128x128], B2 from global ----
    f32x4 acc2[2][4] = {};
    #pragma unroll
    for (int kb = 0; kb < 4; ++kb) {
      const int k = kb * 32 + q * 8;
      const int csw = (kb << 2) + q;       // chunk index k/8
      bf16x8 a[2], b[4];
      #pragma unroll
      for (int mt = 0; mt < 2; ++mt) {
        int row = 32 * wr + 16 * mt + l15;
        a[mt] = *(const bf16x8*)(&h_lds[row * 128 + ((csw ^ (row & 7)) << 3)]);
      }
      #pragma unroll
      for (int nt = 0; nt < 4; ++nt) {
        int n = 64 * wc + 16 * nt + l15;
        b[nt] = *(const bf16x8*)(w2g + n * 128 + k);
      }
      #pragma unroll
      for (int mt = 0; mt < 2; ++mt)
        #pragma unroll
        for (int nt = 0; nt < 4; ++nt)
          acc2[mt][nt] = __builtin_amdgcn_mfma_f32_16x16x32_bf16(a[mt], b[nt], acc2[mt][nt], 0, 0, 0);
    }

    // ---- scatter: atomicAdd into out[target*128 + col] ----
    #pragma unroll
    for (int mt = 0; mt < 2; ++mt)
      #pragma unroll
      for (int r = 0; r < 4; ++r) {
        int row = 32 * wr + 16 * mt + 4 * q + r;
        int2 pr = ((const int2*)adj)[ebase + row];
        int node = clampV(ep ? pr.y : pr.x);
        float* basep = out + (size_t)node * 128 + 64 * wc + l15;
        #pragma unroll
        for (int nt = 0; nt < 4; ++nt)
          unsafeAtomicAdd(basep + 16 * nt, acc2[mt][nt][r]);
      }
  }
}

// ---------------- host launch ----------------------------------------------

extern "C" void kernel_launch(void* const* d_in, const int* in_sizes, int n_in,
                              void* d_out, int out_size, void* d_ws, size_t ws_size,
                              hipStream_t stream) {
  const float* emb = (const float*)d_in[0];
  const int* a0 = (const int*)d_in[1];
  const int* a1 = (const int*)d_in[2];
  const int* a2 = (const int*)d_in[3];
  const int* a3 = (const int*)d_in[4];
  const float* W1 = (const float*)d_in[5];
  const float* W2 = (const float*)d_in[6];
  float* out = (float*)d_out;

  char* ws = (char*)d_ws;
  bf16* embB = (bf16*)ws;                      // 50000*128*2 = 12,800,000 B
  bf16* w1t  = (bf16*)(ws + 12800000);         // 262144*2    =    524,288 B
  bf16* w2t  = (bf16*)(ws + 13324288);         // 131072*2    =    262,144 B

  hipMemsetAsync(d_out, 0, (size_t)V_NODES * DIM * sizeof(float), stream);
  prep_emb_k<<<6250, 256, 0, stream>>>(emb, embB);   // 6.4M elems / 4 / 256
  prep_w1_k<<<1024, 256, 0, stream>>>(W1, w1t);
  prep_w2_k<<<512, 256, 0, stream>>>(W2, w2t);
  edge_k<<<512, 256, 0, stream>>>(embB, a0, a1, a2, a3, w1t, w2t, out);
  relu_k<<<6250, 256, 0, stream>>>(out);
}